// Round 1
// baseline (11015.340 us; speedup 1.0000x reference)
//
#include <hip/hip_runtime.h>

#define N_NODES 200000
#define N_EDGES 6400000
#define N_GRAPHS 2000

// ---------------- layer 1: dim-2 edge aggregation ----------------
__global__ __launch_bounds__(256) void edge_aggr2(
    const int* __restrict__ src, const int* __restrict__ dst,
    const float* __restrict__ x, float* __restrict__ aggr) {
  int e = blockIdx.x * blockDim.x + threadIdx.x;
  if (e >= N_EDGES) return;
  int s = src[e], d = dst[e];
  float2 v = *reinterpret_cast<const float2*>(x + 2 * s);
  atomicAdd(&aggr[2 * d + 0], v.x);
  atomicAdd(&aggr[2 * d + 1], v.y);
}

// ---------------- layer 1: node MLP (2 -> 16 -> 16) ----------------
__global__ __launch_bounds__(256) void node_l1(
    const float* __restrict__ x, const float* __restrict__ aggr,
    const float* __restrict__ Wa, const float* __restrict__ ba,
    const float* __restrict__ Wb, const float* __restrict__ bb,
    float* __restrict__ out) {
  __shared__ float sWa[32], sba[16], sWb[256], sbb[16];
  int t = threadIdx.x;
  if (t < 32) sWa[t] = Wa[t];
  if (t < 16) { sba[t] = ba[t]; sbb[t] = bb[t]; }
  for (int i = t; i < 256; i += blockDim.x) sWb[i] = Wb[i];
  __syncthreads();
  int n = blockIdx.x * blockDim.x + t;
  if (n >= N_NODES) return;
  float2 xv = *reinterpret_cast<const float2*>(x + 2 * n);
  float2 av = *reinterpret_cast<const float2*>(aggr + 2 * n);
  float v0 = xv.x + av.x, v1 = xv.y + av.y;
  float h1[16];
#pragma unroll
  for (int j = 0; j < 16; j++)
    h1[j] = fmaxf(fmaf(v0, sWa[j], fmaf(v1, sWa[16 + j], sba[j])), 0.f);
  float o[16];
#pragma unroll
  for (int j = 0; j < 16; j++) {
    float s = sbb[j];
#pragma unroll
    for (int k = 0; k < 16; k++) s = fmaf(h1[k], sWb[k * 16 + j], s);
    o[j] = fmaxf(s, 0.f);
  }
  float4* op = reinterpret_cast<float4*>(out + n * 16);
#pragma unroll
  for (int q = 0; q < 4; q++)
    op[q] = make_float4(o[4 * q], o[4 * q + 1], o[4 * q + 2], o[4 * q + 3]);
}

// ---------------- dim-16 edge aggregation ----------------
__global__ __launch_bounds__(256) void edge_aggr16(
    const int* __restrict__ src, const int* __restrict__ dst,
    const float* __restrict__ h, float* __restrict__ aggr) {
  int e = blockIdx.x * blockDim.x + threadIdx.x;
  if (e >= N_EDGES) return;
  int s = src[e], d = dst[e];
  const float4* hp = reinterpret_cast<const float4*>(h + 16 * s);
  float4 a = hp[0], b = hp[1], c = hp[2], dd = hp[3];
  float* ap = aggr + 16 * d;
  atomicAdd(ap + 0, a.x);  atomicAdd(ap + 1, a.y);
  atomicAdd(ap + 2, a.z);  atomicAdd(ap + 3, a.w);
  atomicAdd(ap + 4, b.x);  atomicAdd(ap + 5, b.y);
  atomicAdd(ap + 6, b.z);  atomicAdd(ap + 7, b.w);
  atomicAdd(ap + 8, c.x);  atomicAdd(ap + 9, c.y);
  atomicAdd(ap + 10, c.z); atomicAdd(ap + 11, c.w);
  atomicAdd(ap + 12, dd.x); atomicAdd(ap + 13, dd.y);
  atomicAdd(ap + 14, dd.z); atomicAdd(ap + 15, dd.w);
}

// ---------------- node MLP (16 -> 16 -> 16), both relus fused ----------------
__global__ __launch_bounds__(256) void node16(
    const float* __restrict__ hin, const float* __restrict__ aggr,
    const float* __restrict__ Wa, const float* __restrict__ ba,
    const float* __restrict__ Wb, const float* __restrict__ bb,
    float* __restrict__ out) {
  __shared__ float sWa[256], sba[16], sWb[256], sbb[16];
  int t = threadIdx.x;
  if (t < 16) { sba[t] = ba[t]; sbb[t] = bb[t]; }
  for (int i = t; i < 256; i += blockDim.x) { sWa[i] = Wa[i]; sWb[i] = Wb[i]; }
  __syncthreads();
  int n = blockIdx.x * blockDim.x + t;
  if (n >= N_NODES) return;
  float v[16];
  const float4* hp = reinterpret_cast<const float4*>(hin + 16 * n);
  const float4* ap = reinterpret_cast<const float4*>(aggr + 16 * n);
#pragma unroll
  for (int q = 0; q < 4; q++) {
    float4 hv = hp[q], av = ap[q];
    v[4 * q + 0] = hv.x + av.x; v[4 * q + 1] = hv.y + av.y;
    v[4 * q + 2] = hv.z + av.z; v[4 * q + 3] = hv.w + av.w;
  }
  float h1[16];
#pragma unroll
  for (int j = 0; j < 16; j++) {
    float s = sba[j];
#pragma unroll
    for (int k = 0; k < 16; k++) s = fmaf(v[k], sWa[k * 16 + j], s);
    h1[j] = fmaxf(s, 0.f);
  }
  float o[16];
#pragma unroll
  for (int j = 0; j < 16; j++) {
    float s = sbb[j];
#pragma unroll
    for (int k = 0; k < 16; k++) s = fmaf(h1[k], sWb[k * 16 + j], s);
    o[j] = fmaxf(s, 0.f);
  }
  float4* op = reinterpret_cast<float4*>(out + n * 16);
#pragma unroll
  for (int q = 0; q < 4; q++)
    op[q] = make_float4(o[4 * q], o[4 * q + 1], o[4 * q + 2], o[4 * q + 3]);
}

// ---------------- pool: one 64-lane block per graph; batch is sorted ----------------
__global__ __launch_bounds__(64) void pool_kernel(
    const float* __restrict__ h, const int* __restrict__ batch,
    float* __restrict__ g) {
  int gr = blockIdx.x;
  int lo = 0, hi = N_NODES;
  while (lo < hi) { int mid = (lo + hi) >> 1; if (batch[mid] < gr) lo = mid + 1; else hi = mid; }
  int start = lo;
  hi = N_NODES;
  while (lo < hi) { int mid = (lo + hi) >> 1; if (batch[mid] < gr + 1) lo = mid + 1; else hi = mid; }
  int end = lo;
  float acc[16];
#pragma unroll
  for (int j = 0; j < 16; j++) acc[j] = 0.f;
  for (int n = start + threadIdx.x; n < end; n += 64) {
    const float4* hp = reinterpret_cast<const float4*>(h + 16 * n);
#pragma unroll
    for (int q = 0; q < 4; q++) {
      float4 hv = hp[q];
      acc[4 * q + 0] += hv.x; acc[4 * q + 1] += hv.y;
      acc[4 * q + 2] += hv.z; acc[4 * q + 3] += hv.w;
    }
  }
#pragma unroll
  for (int j = 0; j < 16; j++) {
#pragma unroll
    for (int off = 32; off > 0; off >>= 1) acc[j] += __shfl_xor(acc[j], off, 64);
  }
  if (threadIdx.x == 0) {
    float4* gp = reinterpret_cast<float4*>(g + gr * 16);
#pragma unroll
    for (int q = 0; q < 4; q++)
      gp[q] = make_float4(acc[4 * q], acc[4 * q + 1], acc[4 * q + 2], acc[4 * q + 3]);
  }
}

// ---------------- head: relu(g@Wl1+bl1)@Wl2+bl2 ----------------
__global__ __launch_bounds__(256) void head_kernel(
    const float* __restrict__ g,
    const float* __restrict__ Wl1, const float* __restrict__ bl1,
    const float* __restrict__ Wl2, const float* __restrict__ bl2,
    float* __restrict__ out) {
  __shared__ float sW1[256], sb1[16], sW2[16];
  int t = threadIdx.x;
  if (t < 16) { sb1[t] = bl1[t]; sW2[t] = Wl2[t]; }
  for (int i = t; i < 256; i += blockDim.x) sW1[i] = Wl1[i];
  __syncthreads();
  int gr = blockIdx.x * blockDim.x + t;
  if (gr >= N_GRAPHS) return;
  float v[16];
  const float4* gp = reinterpret_cast<const float4*>(g + 16 * gr);
#pragma unroll
  for (int q = 0; q < 4; q++) {
    float4 gv = gp[q];
    v[4 * q + 0] = gv.x; v[4 * q + 1] = gv.y; v[4 * q + 2] = gv.z; v[4 * q + 3] = gv.w;
  }
  float o = bl2[0];
#pragma unroll
  for (int j = 0; j < 16; j++) {
    float s = sb1[j];
#pragma unroll
    for (int k = 0; k < 16; k++) s = fmaf(v[k], sW1[k * 16 + j], s);
    o = fmaf(fmaxf(s, 0.f), sW2[j], o);
  }
  out[gr] = o;
}

extern "C" void kernel_launch(void* const* d_in, const int* in_sizes, int n_in,
                              void* d_out, int out_size, void* d_ws, size_t ws_size,
                              hipStream_t stream) {
  const float* x     = (const float*)d_in[0];
  const int*   ei    = (const int*)d_in[1];
  const int*   src   = ei;
  const int*   dst   = ei + N_EDGES;
  const int*   batch = (const int*)d_in[2];
  const float* W1a = (const float*)d_in[3];  const float* b1a = (const float*)d_in[4];
  const float* W1b = (const float*)d_in[5];  const float* b1b = (const float*)d_in[6];
  const float* W2a = (const float*)d_in[7];  const float* b2a = (const float*)d_in[8];
  const float* W2b = (const float*)d_in[9];  const float* b2b = (const float*)d_in[10];
  const float* W3a = (const float*)d_in[11]; const float* b3a = (const float*)d_in[12];
  const float* W3b = (const float*)d_in[13]; const float* b3b = (const float*)d_in[14];
  const float* Wl1 = (const float*)d_in[15]; const float* bl1 = (const float*)d_in[16];
  const float* Wl2 = (const float*)d_in[17]; const float* bl2 = (const float*)d_in[18];
  float* out = (float*)d_out;

  float* hA   = (float*)d_ws;            // N_NODES*16
  float* hB   = hA + (size_t)N_NODES * 16;
  float* aggr = hB + (size_t)N_NODES * 16;
  float* g    = aggr + (size_t)N_NODES * 16;  // N_GRAPHS*16

  const int EB = 256, NB = 256;
  dim3 egrid((N_EDGES + EB - 1) / EB), ngrid((N_NODES + NB - 1) / NB);

  // layer 1 (dim 2)
  hipMemsetAsync(aggr, 0, (size_t)N_NODES * 2 * sizeof(float), stream);
  edge_aggr2<<<egrid, EB, 0, stream>>>(src, dst, x, aggr);
  node_l1<<<ngrid, NB, 0, stream>>>(x, aggr, W1a, b1a, W1b, b1b, hA);

  // layer 2
  hipMemsetAsync(aggr, 0, (size_t)N_NODES * 16 * sizeof(float), stream);
  edge_aggr16<<<egrid, EB, 0, stream>>>(src, dst, hA, aggr);
  node16<<<ngrid, NB, 0, stream>>>(hA, aggr, W2a, b2a, W2b, b2b, hB);

  // layer 3
  hipMemsetAsync(aggr, 0, (size_t)N_NODES * 16 * sizeof(float), stream);
  edge_aggr16<<<egrid, EB, 0, stream>>>(src, dst, hB, aggr);
  node16<<<ngrid, NB, 0, stream>>>(hB, aggr, W3a, b3a, W3b, b3b, hA);

  // pool + head
  pool_kernel<<<N_GRAPHS, 64, 0, stream>>>(hA, batch, g);
  head_kernel<<<(N_GRAPHS + 255) / 256, 256, 0, stream>>>(g, Wl1, bl1, Wl2, bl2, out);
}

// Round 2
// 1838.323 us; speedup vs baseline: 5.9921x; 5.9921x over previous
//
#include <hip/hip_runtime.h>

#define N_NODES 200000
#define N_EDGES 6400000
#define N_GRAPHS 2000

// ================= CSR build =================
__global__ __launch_bounds__(256) void hist_kernel(
    const int* __restrict__ dst, int* __restrict__ cnt) {
  int e = blockIdx.x * blockDim.x + threadIdx.x;
  if (e >= N_EDGES) return;
  atomicAdd(&cnt[dst[e]], 1);
}

// single-block exclusive scan over 200K counts -> rowptr & cursor
__global__ __launch_bounds__(1024) void scan_kernel(
    const int* __restrict__ cnt, int* __restrict__ rowptr, int* __restrict__ cursor) {
  const int T = 1024;
  const int CH = (N_NODES + T - 1) / T;  // 196
  __shared__ int part[T];
  int t = threadIdx.x;
  int base = t * CH;
  int s = 0;
  for (int i = 0; i < CH; i++) {
    int idx = base + i;
    if (idx < N_NODES) s += cnt[idx];
  }
  part[t] = s;
  __syncthreads();
  // Hillis-Steele inclusive scan (read-sync-write-sync)
  for (int off = 1; off < T; off <<= 1) {
    int v = (t >= off) ? part[t - off] : 0;
    __syncthreads();
    part[t] += v;
    __syncthreads();
  }
  int run = (t > 0) ? part[t - 1] : 0;  // exclusive prefix of this chunk
  for (int i = 0; i < CH; i++) {
    int idx = base + i;
    if (idx < N_NODES) {
      rowptr[idx] = run;
      cursor[idx] = run;
      run += cnt[idx];
    }
  }
  if (t == T - 1) rowptr[N_NODES] = run;
}

__global__ __launch_bounds__(256) void scatter_kernel(
    const int* __restrict__ src, const int* __restrict__ dst,
    int* __restrict__ cursor, int* __restrict__ col) {
  int e = blockIdx.x * blockDim.x + threadIdx.x;
  if (e >= N_EDGES) return;
  int d = dst[e];
  int pos = atomicAdd(&cursor[d], 1);
  col[pos] = src[e];
}

// ================= layer 1: fused gather(dim2) + MLP(2->16->16), outer relu =================
__global__ __launch_bounds__(256) void gin_l1(
    const int* __restrict__ rowptr, const int* __restrict__ col,
    const float* __restrict__ x,
    const float* __restrict__ Wa, const float* __restrict__ ba,
    const float* __restrict__ Wb, const float* __restrict__ bb,
    float* __restrict__ out) {
  __shared__ float sWa[32], sba[16], sWb[256], sbb[16];
  int t = threadIdx.x;
  if (t < 32) sWa[t] = Wa[t];
  if (t < 16) { sba[t] = ba[t]; sbb[t] = bb[t]; }
  for (int i = t; i < 256; i += blockDim.x) sWb[i] = Wb[i];
  __syncthreads();
  int n = blockIdx.x * blockDim.x + t;
  if (n >= N_NODES) return;
  float2 xv = *reinterpret_cast<const float2*>(x + 2 * n);
  float v0 = xv.x, v1 = xv.y;
  int e0 = rowptr[n], e1 = rowptr[n + 1];
  for (int e = e0; e < e1; e++) {
    int s = col[e];
    float2 sv = *reinterpret_cast<const float2*>(x + 2 * s);
    v0 += sv.x;
    v1 += sv.y;
  }
  float h1[16];
#pragma unroll
  for (int j = 0; j < 16; j++)
    h1[j] = fmaxf(fmaf(v0, sWa[j], fmaf(v1, sWa[16 + j], sba[j])), 0.f);
  float o[16];
#pragma unroll
  for (int j = 0; j < 16; j++) {
    float s = sbb[j];
#pragma unroll
    for (int k = 0; k < 16; k++) s = fmaf(h1[k], sWb[k * 16 + j], s);
    o[j] = fmaxf(s, 0.f);
  }
  float4* op = reinterpret_cast<float4*>(out + n * 16);
#pragma unroll
  for (int q = 0; q < 4; q++)
    op[q] = make_float4(o[4 * q], o[4 * q + 1], o[4 * q + 2], o[4 * q + 3]);
}

// ================= layers 2/3: fused gather(dim16) + MLP(16->16->16), outer relu =================
__global__ __launch_bounds__(256) void gin16(
    const int* __restrict__ rowptr, const int* __restrict__ col,
    const float* __restrict__ hin,
    const float* __restrict__ Wa, const float* __restrict__ ba,
    const float* __restrict__ Wb, const float* __restrict__ bb,
    float* __restrict__ out) {
  __shared__ float sWa[256], sba[16], sWb[256], sbb[16];
  int t = threadIdx.x;
  if (t < 16) { sba[t] = ba[t]; sbb[t] = bb[t]; }
  for (int i = t; i < 256; i += blockDim.x) { sWa[i] = Wa[i]; sWb[i] = Wb[i]; }
  __syncthreads();
  int n = blockIdx.x * blockDim.x + t;
  if (n >= N_NODES) return;
  float v[16];
  const float4* hp = reinterpret_cast<const float4*>(hin + 16 * n);
#pragma unroll
  for (int q = 0; q < 4; q++) {
    float4 hv = hp[q];
    v[4 * q + 0] = hv.x; v[4 * q + 1] = hv.y;
    v[4 * q + 2] = hv.z; v[4 * q + 3] = hv.w;
  }
  int e0 = rowptr[n], e1 = rowptr[n + 1];
  for (int e = e0; e < e1; e++) {
    int s = col[e];
    const float4* sp = reinterpret_cast<const float4*>(hin + 16 * s);
#pragma unroll
    for (int q = 0; q < 4; q++) {
      float4 sv = sp[q];
      v[4 * q + 0] += sv.x; v[4 * q + 1] += sv.y;
      v[4 * q + 2] += sv.z; v[4 * q + 3] += sv.w;
    }
  }
  float h1[16];
#pragma unroll
  for (int j = 0; j < 16; j++) {
    float s = sba[j];
#pragma unroll
    for (int k = 0; k < 16; k++) s = fmaf(v[k], sWa[k * 16 + j], s);
    h1[j] = fmaxf(s, 0.f);
  }
  float o[16];
#pragma unroll
  for (int j = 0; j < 16; j++) {
    float s = sbb[j];
#pragma unroll
    for (int k = 0; k < 16; k++) s = fmaf(h1[k], sWb[k * 16 + j], s);
    o[j] = fmaxf(s, 0.f);
  }
  float4* op = reinterpret_cast<float4*>(out + n * 16);
#pragma unroll
  for (int q = 0; q < 4; q++)
    op[q] = make_float4(o[4 * q], o[4 * q + 1], o[4 * q + 2], o[4 * q + 3]);
}

// ================= pool: one 64-lane block per graph; batch is sorted =================
__global__ __launch_bounds__(64) void pool_kernel(
    const float* __restrict__ h, const int* __restrict__ batch,
    float* __restrict__ g) {
  int gr = blockIdx.x;
  int lo = 0, hi = N_NODES;
  while (lo < hi) { int mid = (lo + hi) >> 1; if (batch[mid] < gr) lo = mid + 1; else hi = mid; }
  int start = lo;
  hi = N_NODES;
  while (lo < hi) { int mid = (lo + hi) >> 1; if (batch[mid] < gr + 1) lo = mid + 1; else hi = mid; }
  int end = lo;
  float acc[16];
#pragma unroll
  for (int j = 0; j < 16; j++) acc[j] = 0.f;
  for (int n = start + threadIdx.x; n < end; n += 64) {
    const float4* hp = reinterpret_cast<const float4*>(h + 16 * n);
#pragma unroll
    for (int q = 0; q < 4; q++) {
      float4 hv = hp[q];
      acc[4 * q + 0] += hv.x; acc[4 * q + 1] += hv.y;
      acc[4 * q + 2] += hv.z; acc[4 * q + 3] += hv.w;
    }
  }
#pragma unroll
  for (int j = 0; j < 16; j++) {
#pragma unroll
    for (int off = 32; off > 0; off >>= 1) acc[j] += __shfl_xor(acc[j], off, 64);
  }
  if (threadIdx.x == 0) {
    float4* gp = reinterpret_cast<float4*>(g + gr * 16);
#pragma unroll
    for (int q = 0; q < 4; q++)
      gp[q] = make_float4(acc[4 * q], acc[4 * q + 1], acc[4 * q + 2], acc[4 * q + 3]);
  }
}

// ================= head: relu(g@Wl1+bl1)@Wl2+bl2 =================
__global__ __launch_bounds__(256) void head_kernel(
    const float* __restrict__ g,
    const float* __restrict__ Wl1, const float* __restrict__ bl1,
    const float* __restrict__ Wl2, const float* __restrict__ bl2,
    float* __restrict__ out) {
  __shared__ float sW1[256], sb1[16], sW2[16];
  int t = threadIdx.x;
  if (t < 16) { sb1[t] = bl1[t]; sW2[t] = Wl2[t]; }
  for (int i = t; i < 256; i += blockDim.x) sW1[i] = Wl1[i];
  __syncthreads();
  int gr = blockIdx.x * blockDim.x + t;
  if (gr >= N_GRAPHS) return;
  float v[16];
  const float4* gp = reinterpret_cast<const float4*>(g + 16 * gr);
#pragma unroll
  for (int q = 0; q < 4; q++) {
    float4 gv = gp[q];
    v[4 * q + 0] = gv.x; v[4 * q + 1] = gv.y; v[4 * q + 2] = gv.z; v[4 * q + 3] = gv.w;
  }
  float o = bl2[0];
#pragma unroll
  for (int j = 0; j < 16; j++) {
    float s = sb1[j];
#pragma unroll
    for (int k = 0; k < 16; k++) s = fmaf(v[k], sW1[k * 16 + j], s);
    o = fmaf(fmaxf(s, 0.f), sW2[j], o);
  }
  out[gr] = o;
}

extern "C" void kernel_launch(void* const* d_in, const int* in_sizes, int n_in,
                              void* d_out, int out_size, void* d_ws, size_t ws_size,
                              hipStream_t stream) {
  const float* x     = (const float*)d_in[0];
  const int*   ei    = (const int*)d_in[1];
  const int*   src   = ei;
  const int*   dst   = ei + N_EDGES;
  const int*   batch = (const int*)d_in[2];
  const float* W1a = (const float*)d_in[3];  const float* b1a = (const float*)d_in[4];
  const float* W1b = (const float*)d_in[5];  const float* b1b = (const float*)d_in[6];
  const float* W2a = (const float*)d_in[7];  const float* b2a = (const float*)d_in[8];
  const float* W2b = (const float*)d_in[9];  const float* b2b = (const float*)d_in[10];
  const float* W3a = (const float*)d_in[11]; const float* b3a = (const float*)d_in[12];
  const float* W3b = (const float*)d_in[13]; const float* b3b = (const float*)d_in[14];
  const float* Wl1 = (const float*)d_in[15]; const float* bl1 = (const float*)d_in[16];
  const float* Wl2 = (const float*)d_in[17]; const float* bl2 = (const float*)d_in[18];
  float* out = (float*)d_out;

  // ws layout
  int*   cnt    = (int*)d_ws;                      // N_NODES
  int*   rowptr = cnt + 200064;                    // N_NODES+1 (padded)
  int*   cursor = rowptr + 200064;                 // N_NODES
  int*   col    = cursor + 200064;                 // N_EDGES
  float* hA     = (float*)(col + N_EDGES);         // N_NODES*16
  float* hB     = hA + (size_t)N_NODES * 16;       // N_NODES*16
  float* g      = hB + (size_t)N_NODES * 16;       // N_GRAPHS*16

  const int EB = 256, NB = 256;
  dim3 egrid((N_EDGES + EB - 1) / EB), ngrid((N_NODES + NB - 1) / NB);

  // CSR build (per call; atomic scatter order only perturbs float rounding)
  hipMemsetAsync(cnt, 0, (size_t)N_NODES * sizeof(int), stream);
  hist_kernel<<<egrid, EB, 0, stream>>>(dst, cnt);
  scan_kernel<<<1, 1024, 0, stream>>>(cnt, rowptr, cursor);
  scatter_kernel<<<egrid, EB, 0, stream>>>(src, dst, cursor, col);

  // fused GIN layers
  gin_l1<<<ngrid, NB, 0, stream>>>(rowptr, col, x, W1a, b1a, W1b, b1b, hA);
  gin16<<<ngrid, NB, 0, stream>>>(rowptr, col, hA, W2a, b2a, W2b, b2b, hB);
  gin16<<<ngrid, NB, 0, stream>>>(rowptr, col, hB, W3a, b3a, W3b, b3b, hA);

  // pool + head
  pool_kernel<<<N_GRAPHS, 64, 0, stream>>>(hA, batch, g);
  head_kernel<<<(N_GRAPHS + 255) / 256, 256, 0, stream>>>(g, Wl1, bl1, Wl2, bl2, out);
}

// Round 3
// 1564.819 us; speedup vs baseline: 7.0394x; 1.1748x over previous
//
#include <hip/hip_runtime.h>

#define N_NODES 200000
#define N_EDGES 6400000
#define N_GRAPHS 2000
#define NBUCK 782          // ceil(200000/256) buckets of 256 dst nodes
#define CAP 10240          // per-bucket col capacity (mean 8192, +22 sigma; input fixed)
#define CHUNK 8192         // edges per partition block

// gcur[b] starts at b*CAP; after partition, gcur[b] is the end offset of bucket b
__global__ __launch_bounds__(256) void init_cursor(int* __restrict__ gcur) {
  int b = blockIdx.x * 256 + threadIdx.x;
  if (b < NBUCK) gcur[b] = b * CAP;
}

// one pass: per-block LDS histogram over buckets -> block-level reservation -> packed scatter
__global__ __launch_bounds__(256) void partition_kernel(
    const int* __restrict__ src, const int* __restrict__ dst,
    int* __restrict__ gcur, int* __restrict__ col) {
  __shared__ int cnt[NBUCK];
  __shared__ int base[NBUCK];
  int t = threadIdx.x;
  for (int b = t; b < NBUCK; b += 256) cnt[b] = 0;
  __syncthreads();
  long e0 = (long)blockIdx.x * CHUNK;
  for (int i = t; i < CHUNK; i += 256) {
    long e = e0 + i;
    if (e < N_EDGES) atomicAdd(&cnt[dst[e] >> 8], 1);
  }
  __syncthreads();
  for (int b = t; b < NBUCK; b += 256) {
    int c = cnt[b];
    base[b] = c ? atomicAdd(&gcur[b], c) : 0;
    cnt[b] = 0;  // reuse as local cursor
  }
  __syncthreads();
  for (int i = t; i < CHUNK; i += 256) {
    long e = e0 + i;
    if (e < N_EDGES) {
      int d = dst[e];
      int b = d >> 8;
      int pos = base[b] + atomicAdd(&cnt[b], 1);
      if (pos < (b + 1) * CAP)  // 22-sigma guard, never taken
        col[pos] = (src[e] << 8) | (d & 255);
    }
  }
}

// ---------- layer 1: bucket-local aggregate(dim2) + MLP(2->16->16), outer relu ----------
__global__ __launch_bounds__(256) void gin_l1_bucket(
    const int* __restrict__ gcur, const int* __restrict__ col,
    const float* __restrict__ x,
    const float* __restrict__ Wa, const float* __restrict__ ba,
    const float* __restrict__ Wb, const float* __restrict__ bb,
    float* __restrict__ out) {
  __shared__ float sWa[32], sba[16], sWb[256], sbb[16];
  __shared__ float sAg[256 * 3];  // stride 3: coprime with 32 banks
  int t = threadIdx.x;
  if (t < 32) sWa[t] = Wa[t];
  if (t < 16) { sba[t] = ba[t]; sbb[t] = bb[t]; }
  for (int i = t; i < 256; i += 256) sWb[i] = Wb[i];
  for (int i = t; i < 256 * 3; i += 256) sAg[i] = 0.f;
  __syncthreads();
  int b = blockIdx.x;
  int eBeg = b * CAP;
  int eCnt = gcur[b] - eBeg;
  for (int i = t; i < eCnt; i += 256) {
    int p = col[eBeg + i];
    int s = p >> 8, dl = p & 255;
    float2 sv = *reinterpret_cast<const float2*>(x + 2 * s);
    atomicAdd(&sAg[dl * 3 + 0], sv.x);
    atomicAdd(&sAg[dl * 3 + 1], sv.y);
  }
  __syncthreads();
  int n = b * 256 + t;
  if (n >= N_NODES) return;
  float2 xv = *reinterpret_cast<const float2*>(x + 2 * n);
  float v0 = xv.x + sAg[t * 3 + 0];
  float v1 = xv.y + sAg[t * 3 + 1];
  float h1[16];
#pragma unroll
  for (int j = 0; j < 16; j++)
    h1[j] = fmaxf(fmaf(v0, sWa[j], fmaf(v1, sWa[16 + j], sba[j])), 0.f);
  float o[16];
#pragma unroll
  for (int j = 0; j < 16; j++) {
    float s = sbb[j];
#pragma unroll
    for (int k = 0; k < 16; k++) s = fmaf(h1[k], sWb[k * 16 + j], s);
    o[j] = fmaxf(s, 0.f);
  }
  float4* op = reinterpret_cast<float4*>(out + n * 16);
#pragma unroll
  for (int q = 0; q < 4; q++)
    op[q] = make_float4(o[4 * q], o[4 * q + 1], o[4 * q + 2], o[4 * q + 3]);
}

// ---------- layers 2/3: bucket-local aggregate(dim16) + MLP(16->16->16), outer relu ----------
__global__ __launch_bounds__(256) void gin16_bucket(
    const int* __restrict__ gcur, const int* __restrict__ col,
    const float* __restrict__ hin,
    const float* __restrict__ Wa, const float* __restrict__ ba,
    const float* __restrict__ Wb, const float* __restrict__ bb,
    float* __restrict__ out) {
  __shared__ float sWa[256], sba[16], sWb[256], sbb[16];
  __shared__ float sAg[256 * 17];  // stride 17: bank-conflict-free
  int t = threadIdx.x;
  if (t < 16) { sba[t] = ba[t]; sbb[t] = bb[t]; }
  for (int i = t; i < 256; i += 256) { sWa[i] = Wa[i]; sWb[i] = Wb[i]; }
  for (int i = t; i < 256 * 17; i += 256) sAg[i] = 0.f;
  __syncthreads();
  int b = blockIdx.x;
  int eBeg = b * CAP;
  int eCnt = gcur[b] - eBeg;
#pragma unroll 2
  for (int i = t; i < eCnt; i += 256) {
    int p = col[eBeg + i];
    int s = p >> 8, dl = p & 255;
    const float4* hp = reinterpret_cast<const float4*>(hin + 16 * s);
    float4 A = hp[0], B = hp[1], C = hp[2], D = hp[3];
    float* ag = &sAg[dl * 17];
    atomicAdd(ag + 0, A.x);  atomicAdd(ag + 1, A.y);
    atomicAdd(ag + 2, A.z);  atomicAdd(ag + 3, A.w);
    atomicAdd(ag + 4, B.x);  atomicAdd(ag + 5, B.y);
    atomicAdd(ag + 6, B.z);  atomicAdd(ag + 7, B.w);
    atomicAdd(ag + 8, C.x);  atomicAdd(ag + 9, C.y);
    atomicAdd(ag + 10, C.z); atomicAdd(ag + 11, C.w);
    atomicAdd(ag + 12, D.x); atomicAdd(ag + 13, D.y);
    atomicAdd(ag + 14, D.z); atomicAdd(ag + 15, D.w);
  }
  __syncthreads();
  int n = b * 256 + t;
  if (n >= N_NODES) return;
  float v[16];
  const float4* hp = reinterpret_cast<const float4*>(hin + 16 * n);
#pragma unroll
  for (int q = 0; q < 4; q++) {
    float4 hv = hp[q];
    v[4 * q + 0] = hv.x + sAg[t * 17 + 4 * q + 0];
    v[4 * q + 1] = hv.y + sAg[t * 17 + 4 * q + 1];
    v[4 * q + 2] = hv.z + sAg[t * 17 + 4 * q + 2];
    v[4 * q + 3] = hv.w + sAg[t * 17 + 4 * q + 3];
  }
  float h1[16];
#pragma unroll
  for (int j = 0; j < 16; j++) {
    float s = sba[j];
#pragma unroll
    for (int k = 0; k < 16; k++) s = fmaf(v[k], sWa[k * 16 + j], s);
    h1[j] = fmaxf(s, 0.f);
  }
  float o[16];
#pragma unroll
  for (int j = 0; j < 16; j++) {
    float s = sbb[j];
#pragma unroll
    for (int k = 0; k < 16; k++) s = fmaf(h1[k], sWb[k * 16 + j], s);
    o[j] = fmaxf(s, 0.f);
  }
  float4* op = reinterpret_cast<float4*>(out + n * 16);
#pragma unroll
  for (int q = 0; q < 4; q++)
    op[q] = make_float4(o[4 * q], o[4 * q + 1], o[4 * q + 2], o[4 * q + 3]);
}

// ---------- pool: one 64-lane block per graph; batch is sorted ----------
__global__ __launch_bounds__(64) void pool_kernel(
    const float* __restrict__ h, const int* __restrict__ batch,
    float* __restrict__ g) {
  int gr = blockIdx.x;
  int lo = 0, hi = N_NODES;
  while (lo < hi) { int mid = (lo + hi) >> 1; if (batch[mid] < gr) lo = mid + 1; else hi = mid; }
  int start = lo;
  hi = N_NODES;
  while (lo < hi) { int mid = (lo + hi) >> 1; if (batch[mid] < gr + 1) lo = mid + 1; else hi = mid; }
  int end = lo;
  float acc[16];
#pragma unroll
  for (int j = 0; j < 16; j++) acc[j] = 0.f;
  for (int n = start + threadIdx.x; n < end; n += 64) {
    const float4* hp = reinterpret_cast<const float4*>(h + 16 * n);
#pragma unroll
    for (int q = 0; q < 4; q++) {
      float4 hv = hp[q];
      acc[4 * q + 0] += hv.x; acc[4 * q + 1] += hv.y;
      acc[4 * q + 2] += hv.z; acc[4 * q + 3] += hv.w;
    }
  }
#pragma unroll
  for (int j = 0; j < 16; j++) {
#pragma unroll
    for (int off = 32; off > 0; off >>= 1) acc[j] += __shfl_xor(acc[j], off, 64);
  }
  if (threadIdx.x == 0) {
    float4* gp = reinterpret_cast<float4*>(g + gr * 16);
#pragma unroll
    for (int q = 0; q < 4; q++)
      gp[q] = make_float4(acc[4 * q], acc[4 * q + 1], acc[4 * q + 2], acc[4 * q + 3]);
  }
}

// ---------- head: relu(g@Wl1+bl1)@Wl2+bl2 ----------
__global__ __launch_bounds__(256) void head_kernel(
    const float* __restrict__ g,
    const float* __restrict__ Wl1, const float* __restrict__ bl1,
    const float* __restrict__ Wl2, const float* __restrict__ bl2,
    float* __restrict__ out) {
  __shared__ float sW1[256], sb1[16], sW2[16];
  int t = threadIdx.x;
  if (t < 16) { sb1[t] = bl1[t]; sW2[t] = Wl2[t]; }
  for (int i = t; i < 256; i += 256) sW1[i] = Wl1[i];
  __syncthreads();
  int gr = blockIdx.x * blockDim.x + t;
  if (gr >= N_GRAPHS) return;
  float v[16];
  const float4* gp = reinterpret_cast<const float4*>(g + 16 * gr);
#pragma unroll
  for (int q = 0; q < 4; q++) {
    float4 gv = gp[q];
    v[4 * q + 0] = gv.x; v[4 * q + 1] = gv.y; v[4 * q + 2] = gv.z; v[4 * q + 3] = gv.w;
  }
  float o = bl2[0];
#pragma unroll
  for (int j = 0; j < 16; j++) {
    float s = sb1[j];
#pragma unroll
    for (int k = 0; k < 16; k++) s = fmaf(v[k], sW1[k * 16 + j], s);
    o = fmaf(fmaxf(s, 0.f), sW2[j], o);
  }
  out[gr] = o;
}

extern "C" void kernel_launch(void* const* d_in, const int* in_sizes, int n_in,
                              void* d_out, int out_size, void* d_ws, size_t ws_size,
                              hipStream_t stream) {
  const float* x     = (const float*)d_in[0];
  const int*   ei    = (const int*)d_in[1];
  const int*   src   = ei;
  const int*   dst   = ei + N_EDGES;
  const int*   batch = (const int*)d_in[2];
  const float* W1a = (const float*)d_in[3];  const float* b1a = (const float*)d_in[4];
  const float* W1b = (const float*)d_in[5];  const float* b1b = (const float*)d_in[6];
  const float* W2a = (const float*)d_in[7];  const float* b2a = (const float*)d_in[8];
  const float* W2b = (const float*)d_in[9];  const float* b2b = (const float*)d_in[10];
  const float* W3a = (const float*)d_in[11]; const float* b3a = (const float*)d_in[12];
  const float* W3b = (const float*)d_in[13]; const float* b3b = (const float*)d_in[14];
  const float* Wl1 = (const float*)d_in[15]; const float* bl1 = (const float*)d_in[16];
  const float* Wl2 = (const float*)d_in[17]; const float* bl2 = (const float*)d_in[18];
  float* out = (float*)d_out;

  // ws layout
  int*   gcur = (int*)d_ws;                          // NBUCK (padded 1024)
  int*   col  = gcur + 1024;                         // NBUCK*CAP packed edges
  float* hA   = (float*)(col + (size_t)NBUCK * CAP); // N_NODES*16
  float* hB   = hA + (size_t)N_NODES * 16;           // N_NODES*16
  float* g    = hB + (size_t)N_NODES * 16;           // N_GRAPHS*16

  const int PBLK = (N_EDGES + CHUNK - 1) / CHUNK;    // 782

  init_cursor<<<(NBUCK + 255) / 256, 256, 0, stream>>>(gcur);
  partition_kernel<<<PBLK, 256, 0, stream>>>(src, dst, gcur, col);

  gin_l1_bucket<<<NBUCK, 256, 0, stream>>>(gcur, col, x, W1a, b1a, W1b, b1b, hA);
  gin16_bucket<<<NBUCK, 256, 0, stream>>>(gcur, col, hA, W2a, b2a, W2b, b2b, hB);
  gin16_bucket<<<NBUCK, 256, 0, stream>>>(gcur, col, hB, W3a, b3a, W3b, b3b, hA);

  pool_kernel<<<N_GRAPHS, 64, 0, stream>>>(hA, batch, g);
  head_kernel<<<(N_GRAPHS + 255) / 256, 256, 0, stream>>>(g, Wl1, bl1, Wl2, bl2, out);
}

// Round 4
// 440.667 us; speedup vs baseline: 24.9970x; 3.5510x over previous
//
#include <hip/hip_runtime.h>

#define N_NODES 200000
#define N_EDGES 6400000
#define N_GRAPHS 2000
#define NBUCK 782          // ceil(200000/256) buckets of 256 dst nodes
#define CAP 10240          // per-bucket col capacity (mean 8192, +22 sigma; input fixed)
#define CHUNK 8192         // edges per partition block

// gcur[b] starts at b*CAP; after partition, gcur[b] is the end offset of bucket b
__global__ __launch_bounds__(256) void init_cursor(int* __restrict__ gcur) {
  int b = blockIdx.x * 256 + threadIdx.x;
  if (b < NBUCK) gcur[b] = b * CAP;
}

// pass 1: per-block LDS histogram over buckets -> block-level reservation -> packed scatter
__global__ __launch_bounds__(256) void partition_kernel(
    const int* __restrict__ src, const int* __restrict__ dst,
    int* __restrict__ gcur, int* __restrict__ col) {
  __shared__ int cnt[NBUCK];
  __shared__ int base[NBUCK];
  int t = threadIdx.x;
  for (int b = t; b < NBUCK; b += 256) cnt[b] = 0;
  __syncthreads();
  long e0 = (long)blockIdx.x * CHUNK;
  for (int i = t; i < CHUNK; i += 256) {
    long e = e0 + i;
    if (e < N_EDGES) atomicAdd(&cnt[dst[e] >> 8], 1);
  }
  __syncthreads();
  for (int b = t; b < NBUCK; b += 256) {
    int c = cnt[b];
    base[b] = c ? atomicAdd(&gcur[b], c) : 0;
    cnt[b] = 0;  // reuse as local cursor
  }
  __syncthreads();
  for (int i = t; i < CHUNK; i += 256) {
    long e = e0 + i;
    if (e < N_EDGES) {
      int d = dst[e];
      int b = d >> 8;
      int pos = base[b] + atomicAdd(&cnt[b], 1);
      if (pos < (b + 1) * CAP)  // 22-sigma guard, never taken
        col[pos] = (src[e] << 8) | (d & 255);
    }
  }
}

// pass 2: in-bucket counting sort by dst-local (in-place in col; col becomes src-only,
// grouped by dst). Emits rowstart/rowcnt per node.
__global__ __launch_bounds__(256) void sort_bucket(
    const int* __restrict__ gcur, int* __restrict__ col,
    int* __restrict__ rowstart, int* __restrict__ rowcnt) {
  __shared__ int sEdge[CAP];      // 40 KB staging of this bucket's packed edges
  __shared__ int hist[256], sc[256], lcur[256];
  int t = threadIdx.x;
  int b = blockIdx.x;
  int beg = b * CAP;
  int cnt = gcur[b] - beg;
  if (cnt > CAP) cnt = CAP;
  hist[t] = 0;
  __syncthreads();
  for (int i = t; i < cnt; i += 256) {
    int p = col[beg + i];
    sEdge[i] = p;
    atomicAdd(&hist[p & 255], 1);
  }
  __syncthreads();
  // exclusive scan of hist -> sc
  sc[t] = hist[t];
  __syncthreads();
  for (int off = 1; off < 256; off <<= 1) {
    int v = (t >= off) ? sc[t - off] : 0;
    __syncthreads();
    sc[t] += v;
    __syncthreads();
  }
  int excl = sc[t] - hist[t];
  lcur[t] = excl;
  int n = b * 256 + t;
  if (n < N_NODES) {
    rowstart[n] = beg + excl;
    rowcnt[n] = hist[t];
  }
  __syncthreads();
  for (int i = t; i < cnt; i += 256) {
    int p = sEdge[i];
    int pos = atomicAdd(&lcur[p & 255], 1);
    col[beg + pos] = p >> 8;  // store src only, grouped by dst-local
  }
}

// ---------- layer 1 aggregation: one wave per node, dim 2 ----------
__global__ __launch_bounds__(256) void aggr2_wave(
    const int* __restrict__ rowstart, const int* __restrict__ rowcnt,
    const int* __restrict__ col, const float* __restrict__ x,
    float* __restrict__ agg) {
  int n = blockIdx.x * 4 + (threadIdx.x >> 6);  // 200000 = 50000*4 exactly
  int lane = threadIdx.x & 63;
  int e0 = rowstart[n], c = rowcnt[n];
  float a0 = 0.f, a1 = 0.f;
  for (int basei = 0; basei < c; basei += 64) {
    int idx = basei + lane;
    if (idx < c) {
      int s = col[e0 + idx];
      float2 u = *reinterpret_cast<const float2*>(x + 2 * s);
      a0 += u.x; a1 += u.y;
    }
  }
#pragma unroll
  for (int off = 1; off <= 32; off <<= 1) {
    a0 += __shfl_xor(a0, off, 64);
    a1 += __shfl_xor(a1, off, 64);
  }
  if (lane == 0) {
    *reinterpret_cast<float2*>(agg + 2 * n) = make_float2(a0, a1);
  }
}

// ---------- layers 2/3 aggregation: one wave per node, dim 16 ----------
__global__ __launch_bounds__(256) void aggr16_wave(
    const int* __restrict__ rowstart, const int* __restrict__ rowcnt,
    const int* __restrict__ col, const float* __restrict__ h,
    float* __restrict__ agg) {
  int n = blockIdx.x * 4 + (threadIdx.x >> 6);
  int lane = threadIdx.x & 63;
  int e0 = rowstart[n], c = rowcnt[n];
  float a[8];
#pragma unroll
  for (int j = 0; j < 8; j++) a[j] = 0.f;
  int half = lane & 1;
  for (int basei = 0; basei < c; basei += 32) {
    int idx = basei + (lane >> 1);
    if (idx < c) {
      int s = col[e0 + idx];
      const float4* p = reinterpret_cast<const float4*>(h + 16 * s + 8 * half);
      float4 u = p[0], v = p[1];
      a[0] += u.x; a[1] += u.y; a[2] += u.z; a[3] += u.w;
      a[4] += v.x; a[5] += v.y; a[6] += v.z; a[7] += v.w;
    }
  }
  // reduce over the 32 edge-slots (lanes with same parity)
#pragma unroll
  for (int off = 2; off <= 32; off <<= 1) {
#pragma unroll
    for (int j = 0; j < 8; j++) a[j] += __shfl_xor(a[j], off, 64);
  }
  if (lane < 2) {
    float* dstp = agg + n * 16 + 8 * lane;
    *reinterpret_cast<float4*>(dstp) = make_float4(a[0], a[1], a[2], a[3]);
    *reinterpret_cast<float4*>(dstp + 4) = make_float4(a[4], a[5], a[6], a[7]);
  }
}

// ---------- layer 1 node MLP (2 -> 16 -> 16), outer relu ----------
__global__ __launch_bounds__(256) void node_l1(
    const float* __restrict__ x, const float* __restrict__ aggr,
    const float* __restrict__ Wa, const float* __restrict__ ba,
    const float* __restrict__ Wb, const float* __restrict__ bb,
    float* __restrict__ out) {
  __shared__ float sWa[32], sba[16], sWb[256], sbb[16];
  int t = threadIdx.x;
  if (t < 32) sWa[t] = Wa[t];
  if (t < 16) { sba[t] = ba[t]; sbb[t] = bb[t]; }
  for (int i = t; i < 256; i += 256) sWb[i] = Wb[i];
  __syncthreads();
  int n = blockIdx.x * blockDim.x + t;
  if (n >= N_NODES) return;
  float2 xv = *reinterpret_cast<const float2*>(x + 2 * n);
  float2 av = *reinterpret_cast<const float2*>(aggr + 2 * n);
  float v0 = xv.x + av.x, v1 = xv.y + av.y;
  float h1[16];
#pragma unroll
  for (int j = 0; j < 16; j++)
    h1[j] = fmaxf(fmaf(v0, sWa[j], fmaf(v1, sWa[16 + j], sba[j])), 0.f);
  float o[16];
#pragma unroll
  for (int j = 0; j < 16; j++) {
    float s = sbb[j];
#pragma unroll
    for (int k = 0; k < 16; k++) s = fmaf(h1[k], sWb[k * 16 + j], s);
    o[j] = fmaxf(s, 0.f);
  }
  float4* op = reinterpret_cast<float4*>(out + n * 16);
#pragma unroll
  for (int q = 0; q < 4; q++)
    op[q] = make_float4(o[4 * q], o[4 * q + 1], o[4 * q + 2], o[4 * q + 3]);
}

// ---------- layers 2/3 node MLP (16 -> 16 -> 16), outer relu ----------
__global__ __launch_bounds__(256) void node16(
    const float* __restrict__ hin, const float* __restrict__ aggr,
    const float* __restrict__ Wa, const float* __restrict__ ba,
    const float* __restrict__ Wb, const float* __restrict__ bb,
    float* __restrict__ out) {
  __shared__ float sWa[256], sba[16], sWb[256], sbb[16];
  int t = threadIdx.x;
  if (t < 16) { sba[t] = ba[t]; sbb[t] = bb[t]; }
  for (int i = t; i < 256; i += 256) { sWa[i] = Wa[i]; sWb[i] = Wb[i]; }
  __syncthreads();
  int n = blockIdx.x * blockDim.x + t;
  if (n >= N_NODES) return;
  float v[16];
  const float4* hp = reinterpret_cast<const float4*>(hin + 16 * n);
  const float4* ap = reinterpret_cast<const float4*>(aggr + 16 * n);
#pragma unroll
  for (int q = 0; q < 4; q++) {
    float4 hv = hp[q], av = ap[q];
    v[4 * q + 0] = hv.x + av.x; v[4 * q + 1] = hv.y + av.y;
    v[4 * q + 2] = hv.z + av.z; v[4 * q + 3] = hv.w + av.w;
  }
  float h1[16];
#pragma unroll
  for (int j = 0; j < 16; j++) {
    float s = sba[j];
#pragma unroll
    for (int k = 0; k < 16; k++) s = fmaf(v[k], sWa[k * 16 + j], s);
    h1[j] = fmaxf(s, 0.f);
  }
  float o[16];
#pragma unroll
  for (int j = 0; j < 16; j++) {
    float s = sbb[j];
#pragma unroll
    for (int k = 0; k < 16; k++) s = fmaf(h1[k], sWb[k * 16 + j], s);
    o[j] = fmaxf(s, 0.f);
  }
  float4* op = reinterpret_cast<float4*>(out + n * 16);
#pragma unroll
  for (int q = 0; q < 4; q++)
    op[q] = make_float4(o[4 * q], o[4 * q + 1], o[4 * q + 2], o[4 * q + 3]);
}

// ---------- pool: one 64-lane block per graph; batch is sorted ----------
__global__ __launch_bounds__(64) void pool_kernel(
    const float* __restrict__ h, const int* __restrict__ batch,
    float* __restrict__ g) {
  int gr = blockIdx.x;
  int lo = 0, hi = N_NODES;
  while (lo < hi) { int mid = (lo + hi) >> 1; if (batch[mid] < gr) lo = mid + 1; else hi = mid; }
  int start = lo;
  hi = N_NODES;
  while (lo < hi) { int mid = (lo + hi) >> 1; if (batch[mid] < gr + 1) lo = mid + 1; else hi = mid; }
  int end = lo;
  float acc[16];
#pragma unroll
  for (int j = 0; j < 16; j++) acc[j] = 0.f;
  for (int n = start + threadIdx.x; n < end; n += 64) {
    const float4* hp = reinterpret_cast<const float4*>(h + 16 * n);
#pragma unroll
    for (int q = 0; q < 4; q++) {
      float4 hv = hp[q];
      acc[4 * q + 0] += hv.x; acc[4 * q + 1] += hv.y;
      acc[4 * q + 2] += hv.z; acc[4 * q + 3] += hv.w;
    }
  }
#pragma unroll
  for (int j = 0; j < 16; j++) {
#pragma unroll
    for (int off = 32; off > 0; off >>= 1) acc[j] += __shfl_xor(acc[j], off, 64);
  }
  if (threadIdx.x == 0) {
    float4* gp = reinterpret_cast<float4*>(g + gr * 16);
#pragma unroll
    for (int q = 0; q < 4; q++)
      gp[q] = make_float4(acc[4 * q], acc[4 * q + 1], acc[4 * q + 2], acc[4 * q + 3]);
  }
}

// ---------- head: relu(g@Wl1+bl1)@Wl2+bl2 ----------
__global__ __launch_bounds__(256) void head_kernel(
    const float* __restrict__ g,
    const float* __restrict__ Wl1, const float* __restrict__ bl1,
    const float* __restrict__ Wl2, const float* __restrict__ bl2,
    float* __restrict__ out) {
  __shared__ float sW1[256], sb1[16], sW2[16];
  int t = threadIdx.x;
  if (t < 16) { sb1[t] = bl1[t]; sW2[t] = Wl2[t]; }
  for (int i = t; i < 256; i += 256) sW1[i] = Wl1[i];
  __syncthreads();
  int gr = blockIdx.x * blockDim.x + t;
  if (gr >= N_GRAPHS) return;
  float v[16];
  const float4* gp = reinterpret_cast<const float4*>(g + 16 * gr);
#pragma unroll
  for (int q = 0; q < 4; q++) {
    float4 gv = gp[q];
    v[4 * q + 0] = gv.x; v[4 * q + 1] = gv.y; v[4 * q + 2] = gv.z; v[4 * q + 3] = gv.w;
  }
  float o = bl2[0];
#pragma unroll
  for (int j = 0; j < 16; j++) {
    float s = sb1[j];
#pragma unroll
    for (int k = 0; k < 16; k++) s = fmaf(v[k], sW1[k * 16 + j], s);
    o = fmaf(fmaxf(s, 0.f), sW2[j], o);
  }
  out[gr] = o;
}

extern "C" void kernel_launch(void* const* d_in, const int* in_sizes, int n_in,
                              void* d_out, int out_size, void* d_ws, size_t ws_size,
                              hipStream_t stream) {
  const float* x     = (const float*)d_in[0];
  const int*   ei    = (const int*)d_in[1];
  const int*   src   = ei;
  const int*   dst   = ei + N_EDGES;
  const int*   batch = (const int*)d_in[2];
  const float* W1a = (const float*)d_in[3];  const float* b1a = (const float*)d_in[4];
  const float* W1b = (const float*)d_in[5];  const float* b1b = (const float*)d_in[6];
  const float* W2a = (const float*)d_in[7];  const float* b2a = (const float*)d_in[8];
  const float* W2b = (const float*)d_in[9];  const float* b2b = (const float*)d_in[10];
  const float* W3a = (const float*)d_in[11]; const float* b3a = (const float*)d_in[12];
  const float* W3b = (const float*)d_in[13]; const float* b3b = (const float*)d_in[14];
  const float* Wl1 = (const float*)d_in[15]; const float* bl1 = (const float*)d_in[16];
  const float* Wl2 = (const float*)d_in[17]; const float* bl2 = (const float*)d_in[18];
  float* out = (float*)d_out;

  // ws layout
  int*   gcur     = (int*)d_ws;                         // NBUCK (padded 1024)
  int*   col      = gcur + 1024;                        // NBUCK*CAP packed/sorted edges
  int*   rowstart = col + (size_t)NBUCK * CAP;          // N_NODES (padded)
  int*   rowcnt   = rowstart + 200192;                  // N_NODES (padded)
  float* agg      = (float*)(rowcnt + 200192);          // N_NODES*16
  float* hA       = agg + (size_t)N_NODES * 16;         // N_NODES*16
  float* hB       = hA + (size_t)N_NODES * 16;          // N_NODES*16
  float* g        = hB + (size_t)N_NODES * 16;          // N_GRAPHS*16

  const int PBLK = (N_EDGES + CHUNK - 1) / CHUNK;       // 782
  const int NWAVE_BLK = N_NODES / 4;                    // 50000 (exact)
  dim3 ngrid((N_NODES + 255) / 256);

  init_cursor<<<(NBUCK + 255) / 256, 256, 0, stream>>>(gcur);
  partition_kernel<<<PBLK, 256, 0, stream>>>(src, dst, gcur, col);
  sort_bucket<<<NBUCK, 256, 0, stream>>>(gcur, col, rowstart, rowcnt);

  // layer 1
  aggr2_wave<<<NWAVE_BLK, 256, 0, stream>>>(rowstart, rowcnt, col, x, agg);
  node_l1<<<ngrid, 256, 0, stream>>>(x, agg, W1a, b1a, W1b, b1b, hA);
  // layer 2
  aggr16_wave<<<NWAVE_BLK, 256, 0, stream>>>(rowstart, rowcnt, col, hA, agg);
  node16<<<ngrid, 256, 0, stream>>>(hA, agg, W2a, b2a, W2b, b2b, hB);
  // layer 3
  aggr16_wave<<<NWAVE_BLK, 256, 0, stream>>>(rowstart, rowcnt, col, hB, agg);
  node16<<<ngrid, 256, 0, stream>>>(hB, agg, W3a, b3a, W3b, b3b, hA);

  pool_kernel<<<N_GRAPHS, 64, 0, stream>>>(hA, batch, g);
  head_kernel<<<(N_GRAPHS + 255) / 256, 256, 0, stream>>>(g, Wl1, bl1, Wl2, bl2, out);
}